// Round 1
// baseline (277.521 us; speedup 1.0000x reference)
//
#include <hip/hip_runtime.h>

// MessagePassing: 10 iterations of 3x3 per-pixel-weighted smoothing.
//   input  [8, 64, 128, 128] f32
//   weight [8,  9, 128, 128] f32  (normalized per pixel: w / (sum_taps + 1e-5))
//   out    [8, 64, 128, 128] f32
// Strategy: normalize weights once into ws; then 10 ping-pong stencil launches.
// Each step-thread: fixed (n,h,4-wide w strip), weights in 36 VGPRs, loop 8 channels.

#define NB   8
#define CC   64
#define HH   128
#define WW   128
#define TAPS 9
#define PLANE (HH * WW)        // 16384
#define CHW   (CC * PLANE)
#define CPT  8                 // channels per thread
#define NWFLOATS (NB * TAPS * PLANE)   // 1,179,648 floats (4.7 MB)

__global__ __launch_bounds__(256) void mp_norm_kernel(const float* __restrict__ w,
                                                      float* __restrict__ nw) {
    int tid = blockIdx.x * 256 + threadIdx.x;       // 32768 threads total
    int wg = tid & 31;                               // w-group (4 pixels)
    int h  = (tid >> 5) & 127;
    int n  = tid >> 12;
    int base = n * TAPS * PLANE + h * WW + wg * 4;   // 16B aligned
    float4 t[TAPS];
    float sx = 1e-5f, sy = 1e-5f, sz = 1e-5f, sw = 1e-5f;
#pragma unroll
    for (int k = 0; k < TAPS; ++k) {
        t[k] = *reinterpret_cast<const float4*>(w + base + k * PLANE);
        sx += t[k].x; sy += t[k].y; sz += t[k].z; sw += t[k].w;
    }
    float rx = 1.0f / sx, ry = 1.0f / sy, rz = 1.0f / sz, rw = 1.0f / sw;
#pragma unroll
    for (int k = 0; k < TAPS; ++k) {
        float4 o = make_float4(t[k].x * rx, t[k].y * ry, t[k].z * rz, t[k].w * rw);
        *reinterpret_cast<float4*>(nw + base + k * PLANE) = o;
    }
}

__global__ __launch_bounds__(256) void mp_step_kernel(const float* __restrict__ src,
                                                      float* __restrict__ dst,
                                                      const float* __restrict__ nw) {
    int tid = blockIdx.x * 256 + threadIdx.x;        // 262144 threads total
    int wg = tid & 31;           int w0 = wg << 2;   // 4-wide strip
    int cg = (tid >> 5) & 7;     int c0 = cg * CPT;
    int h  = (tid >> 8) & 127;
    int n  = tid >> 15;

    // 36 normalized weights into registers (shared across the 8 channels)
    const float* nwp = nw + n * TAPS * PLANE + h * WW + w0;
    float4 wt[TAPS];
#pragma unroll
    for (int k = 0; k < TAPS; ++k)
        wt[k] = *reinterpret_cast<const float4*>(nwp + k * PLANE);

    const bool has_l = (w0 > 0);
    const bool has_r = (w0 < WW - 4);

    const float* sp = src + (size_t)n * CHW + (size_t)c0 * PLANE + h * WW + w0;
    float*       dp = dst + (size_t)n * CHW + (size_t)c0 * PLANE + h * WW + w0;

#pragma unroll
    for (int c = 0; c < CPT; ++c) {
        const float* p = sp + c * PLANE;
        float a0 = 0.f, a1 = 0.f, a2 = 0.f, a3 = 0.f;
#pragma unroll
        for (int di = 0; di < 3; ++di) {
            bool rok = (di == 1) ? true : (di == 0 ? (h > 0) : (h < HH - 1));
            const float* rp = p + (di - 1) * WW;
            float xv0, xv1, xv2, xv3, xv4, xv5;
            if (rok) {
                float4 mid = *reinterpret_cast<const float4*>(rp);  // aligned
                xv0 = has_l ? rp[-1] : 0.f;
                xv1 = mid.x; xv2 = mid.y; xv3 = mid.z; xv4 = mid.w;
                xv5 = has_r ? rp[4] : 0.f;
            } else {
                xv0 = xv1 = xv2 = xv3 = xv4 = xv5 = 0.f;
            }
            // dj = 0
            {
                const float4 wv = wt[di * 3 + 0];
                a0 = fmaf(xv0, wv.x, a0);
                a1 = fmaf(xv1, wv.y, a1);
                a2 = fmaf(xv2, wv.z, a2);
                a3 = fmaf(xv3, wv.w, a3);
            }
            // dj = 1
            {
                const float4 wv = wt[di * 3 + 1];
                a0 = fmaf(xv1, wv.x, a0);
                a1 = fmaf(xv2, wv.y, a1);
                a2 = fmaf(xv3, wv.z, a2);
                a3 = fmaf(xv4, wv.w, a3);
            }
            // dj = 2
            {
                const float4 wv = wt[di * 3 + 2];
                a0 = fmaf(xv2, wv.x, a0);
                a1 = fmaf(xv3, wv.y, a1);
                a2 = fmaf(xv4, wv.z, a2);
                a3 = fmaf(xv5, wv.w, a3);
            }
        }
        *reinterpret_cast<float4*>(dp + c * PLANE) = make_float4(a0, a1, a2, a3);
    }
}

extern "C" void kernel_launch(void* const* d_in, const int* in_sizes, int n_in,
                              void* d_out, int out_size, void* d_ws, size_t ws_size,
                              hipStream_t stream) {
    const float* input  = (const float*)d_in[0];
    const float* weight = (const float*)d_in[1];
    float* out = (float*)d_out;

    float* nw = (float*)d_ws;               // 4.72 MB normalized weights
    float* B0 = nw + NWFLOATS;              // 33.5 MB ping buffer

    mp_norm_kernel<<<128, 256, 0, stream>>>(weight, nw);

    // step 1: input -> B0
    mp_step_kernel<<<1024, 256, 0, stream>>>(input, B0, nw);
    // steps 2..10 alternate; even steps write d_out, so step 10 lands in d_out
    const float* s = B0;
    float* d = out;
    for (int i = 2; i <= 10; ++i) {
        mp_step_kernel<<<1024, 256, 0, stream>>>(s, d, nw);
        const float* ns = d;
        d = (d == out) ? B0 : out;
        s = ns;
    }
}

// Round 2
// 205.795 us; speedup vs baseline: 1.3485x; 1.3485x over previous
//
#include <hip/hip_runtime.h>

// MessagePassing: 10 iterations of 3x3 per-pixel-weighted smoothing, fully fused.
//   input  [8, 64, 128, 128] f32, weight [8, 9, 128, 128] f32 -> out [8, 64, 128, 128] f32
// One fused kernel: 32x32 output tile, 52x52 LDS region (halo 10), shrinking valid
// region, 10 steps in LDS ping-pong (4 channels/chunk as float4), per-thread weights
// (4 px x 9 taps) in registers reused across 4 chunks x 10 steps.

#define NB    8
#define CC    64
#define HH    128
#define WW    128
#define TAPS  9
#define PLANE (HH * WW)

#define TILE    32
#define HALO    10
#define REG     52          // TILE + 2*HALO
#define RSTR    57          // LDS row stride in float4 (52 + 5 pad; 228 floats = 4-bank shift/row)
#define NSTRIPS 13          // 52 / 4
#define NTH     704         // 11 waves
#define ACTIVE  676         // 52 rows * 13 strips
#define NSTEPS  10
#define CGRP    16          // channels per block
#define CSUB    4           // channels per LDS chunk (float4)

__device__ __forceinline__ float4 fma4(const float4 a, const float s, const float4 c) {
    return make_float4(fmaf(a.x, s, c.x), fmaf(a.y, s, c.y),
                       fmaf(a.z, s, c.z), fmaf(a.w, s, c.w));
}

__global__ __launch_bounds__(256) void mp_norm_kernel(const float* __restrict__ w,
                                                      float* __restrict__ nw) {
    int tid = blockIdx.x * 256 + threadIdx.x;       // 32768 threads
    int wg = tid & 31;
    int h  = (tid >> 5) & 127;
    int n  = tid >> 12;
    int base = n * TAPS * PLANE + h * WW + wg * 4;
    float4 t[TAPS];
    float sx = 1e-5f, sy = 1e-5f, sz = 1e-5f, sw = 1e-5f;
#pragma unroll
    for (int k = 0; k < TAPS; ++k) {
        t[k] = *reinterpret_cast<const float4*>(w + base + k * PLANE);
        sx += t[k].x; sy += t[k].y; sz += t[k].z; sw += t[k].w;
    }
    float rx = 1.0f / sx, ry = 1.0f / sy, rz = 1.0f / sz, rw = 1.0f / sw;
#pragma unroll
    for (int k = 0; k < TAPS; ++k) {
        float4 o = make_float4(t[k].x * rx, t[k].y * ry, t[k].z * rz, t[k].w * rw);
        *reinterpret_cast<float4*>(nw + base + k * PLANE) = o;
    }
}

__global__ __launch_bounds__(NTH, 1) void mp_fused_kernel(const float* __restrict__ src,
                                                          float* __restrict__ dst,
                                                          const float* __restrict__ nw) {
    __shared__ float4 bufA[REG * RSTR];
    __shared__ float4 bufB[REG * RSTR];

    const int bid  = blockIdx.x;            // 512 blocks
    const int n    = bid >> 6;
    const int tile = (bid >> 2) & 15;
    const int cg   = bid & 3;
    const int tr0  = (tile >> 2) * TILE;
    const int tc0  = (tile & 3) * TILE;
    const int cb   = cg * CGRP;

    const int t     = threadIdx.x;
    const bool act  = t < ACTIVE;
    const int row   = t / NSTRIPS;          // 0..51
    const int strip = t - row * NSTRIPS;    // 0..12
    const int w0    = strip * 4;

    // ---- per-thread weights: 4 px x 9 taps, held in registers for whole kernel ----
    float wt[TAPS][4];
    {
        const int gr = tr0 - HALO + row;
        const bool rin = act && gr >= 0 && gr < HH;
        const float* nwb = nw + (size_t)n * TAPS * PLANE;
#pragma unroll
        for (int i = 0; i < 4; ++i) {
            const int gc = tc0 - HALO + w0 + i;
            const bool in = rin && gc >= 0 && gc < WW;
            const int off = in ? (gr * WW + gc) : 0;
#pragma unroll
            for (int k = 0; k < TAPS; ++k)
                wt[k][i] = in ? nwb[k * PLANE + off] : 0.f;   // 0-weights => out-of-image px stay 0
        }
    }

    for (int ch = 0; ch < CGRP; ch += CSUB) {
        const float* sp = src + ((size_t)n * CC + cb + ch) * PLANE;

        // ---- load 52x52 region x 4 channels into bufA (coalesced, zero-padded) ----
        for (int idx = t; idx < REG * REG; idx += NTH) {
            const int r = idx / REG;
            const int c = idx - r * REG;
            const int gr = tr0 - HALO + r;
            const int gc = tc0 - HALO + c;
            float4 v = make_float4(0.f, 0.f, 0.f, 0.f);
            if (gr >= 0 && gr < HH && gc >= 0 && gc < WW) {
                const int o = gr * WW + gc;
                v.x = sp[o];
                v.y = sp[PLANE + o];
                v.z = sp[2 * PLANE + o];
                v.w = sp[3 * PLANE + o];
            }
            bufA[r * RSTR + c] = v;
        }
        __syncthreads();

        // ---- 10 fused steps with shrinking valid region ----
        float4* pin  = bufA;
        float4* pout = bufB;
        for (int s = 0; s < NSTEPS; ++s) {
            const int lo = s + 1;
            const int hi = 50 - s;
            if (act && row >= lo && row <= hi) {
                const float4 z = make_float4(0.f, 0.f, 0.f, 0.f);
                float4 a0 = z, a1 = z, a2 = z, a3 = z;
#pragma unroll
                for (int di = 0; di < 3; ++di) {
                    const float4* rp = pin + (row - 1 + di) * RSTR + w0;
                    const float4 x0 = (w0 > 0) ? rp[-1] : z;       // feeds only invalid col 0
                    const float4 x1 = rp[0];
                    const float4 x2 = rp[1];
                    const float4 x3 = rp[2];
                    const float4 x4 = rp[3];
                    const float4 x5 = (w0 + 4 < REG) ? rp[4] : z;  // feeds only invalid col 51
                    const int k = di * 3;
                    // dj = 0: px_i <- x_i
                    a0 = fma4(x0, wt[k][0], a0);     a1 = fma4(x1, wt[k][1], a1);
                    a2 = fma4(x2, wt[k][2], a2);     a3 = fma4(x3, wt[k][3], a3);
                    // dj = 1: px_i <- x_{i+1}
                    a0 = fma4(x1, wt[k + 1][0], a0); a1 = fma4(x2, wt[k + 1][1], a1);
                    a2 = fma4(x3, wt[k + 1][2], a2); a3 = fma4(x4, wt[k + 1][3], a3);
                    // dj = 2: px_i <- x_{i+2}
                    a0 = fma4(x2, wt[k + 2][0], a0); a1 = fma4(x3, wt[k + 2][1], a1);
                    a2 = fma4(x4, wt[k + 2][2], a2); a3 = fma4(x5, wt[k + 2][3], a3);
                }
                float4* op = pout + row * RSTR + w0;
                op[0] = a0; op[1] = a1; op[2] = a2; op[3] = a3;
            }
            __syncthreads();
            float4* tmp = pin; pin = pout; pout = tmp;
        }

        // ---- write 32x32 core x 4 channels (result back in bufA after 10 steps) ----
        float* dp = dst + ((size_t)n * CC + cb + ch) * PLANE;
        for (int idx = t; idx < TILE * TILE; idx += NTH) {
            const int r = idx >> 5;
            const int c = idx & 31;
            const float4 v = pin[(r + HALO) * RSTR + (c + HALO)];
            const int o = (tr0 + r) * WW + tc0 + c;
            dp[o] = v.x;
            dp[PLANE + o] = v.y;
            dp[2 * PLANE + o] = v.z;
            dp[3 * PLANE + o] = v.w;
        }
        __syncthreads();   // protect bufA before next chunk's load
    }
}

extern "C" void kernel_launch(void* const* d_in, const int* in_sizes, int n_in,
                              void* d_out, int out_size, void* d_ws, size_t ws_size,
                              hipStream_t stream) {
    const float* input  = (const float*)d_in[0];
    const float* weight = (const float*)d_in[1];
    float* out = (float*)d_out;
    float* nw  = (float*)d_ws;   // 4.72 MB normalized weights

    mp_norm_kernel<<<128, 256, 0, stream>>>(weight, nw);
    mp_fused_kernel<<<512, NTH, 0, stream>>>(input, out, nw);
}